// Round 3
// baseline (74.879 us; speedup 1.0000x reference)
//
#include <hip/hip_runtime.h>
#include <hip/hip_bf16.h>
#include <math.h>

#define BATCH 256
#define SEQL  4096
#define DIMC  256
#define NPAT  160
#define CNT   (BATCH * SEQL)     // per-stream element count (over B,L)
#define EPS   1e-3f

typedef unsigned int uint;
typedef unsigned short ushort_t;

// ---------------- shared helpers ----------------------------------------------
__device__ __forceinline__ int pad_mask(int type) {
    return (type == 0) ? 0 : (type == 1) ? 3 : (type == 2) ? 1 : (type == 3) ? 16 : 24;
}

// tap value for extended-pattern q, index k in [0,6): k==5 is the constant 1.
__device__ __forceinline__ float tap6(int q, int k) {
    if (k == 5) return 1.0f;
    const int type = q >> 5, bits = q & 31;
    const int pm = pad_mask(type);
    if ((pm >> k) & 1) return 0.0f;
    return ((bits >> k) & 1) ? 1.0f : -1.0f;
}

__device__ __forceinline__ int tri_idx(int k, int l) {
    return k * 6 - (k * (k - 1)) / 2 + (l - k);
}

__device__ __forceinline__ float fast_elu(float x) {
    return x > 0.0f ? x : (__expf(x) - 1.0f);
}

__device__ __forceinline__ int pat_type(int t) {
    if (t >= 2 && t < SEQL - 2) return 0;
    if (t == 0) return 1;
    if (t == 1) return 2;
    if (t == SEQL - 2) return 3;
    return 4;
}

// legacy byte-array pattern (fallback path)
__device__ __forceinline__ int pat_q(const unsigned char* bits, int t) {
    unsigned b = 0;
#pragma unroll
    for (int k = 0; k < 5; ++k) {
        int pos = t + k - 2;
        unsigned v = (pos >= 0 && pos < SEQL) ? (unsigned)bits[pos] : 0u;
        b |= v << k;
    }
    return pat_type(t) * 32 + (int)b;
}

struct PtrPack { const float* p[18]; };  // per stream: Wc, bc, g, be, Wf, bf

// =============================================================================
// PATH A (fast): prep -> etab2 -> outtab2 -> write2
// =============================================================================

// ---------------- k_prep: bit-pack, codes, partial histograms ------------------
// 256 blocks (one row each) x 512 threads.
__global__ __launch_bounds__(512) void k_prep(const float* __restrict__ x,
                                              const int* __restrict__ perms,
                                              uint* __restrict__ part,
                                              ushort_t* __restrict__ codes) {
    __shared__ uint xw[130];    // bit-packed row, 1-word zero sentinel each end
    __shared__ uint xwI[130];
    __shared__ uint h[2 * NPAT];
    const int b = blockIdx.x, tid = threadIdx.x;
    const int lane = tid & 63;

    for (int i = tid; i < 2 * NPAT; i += 512) h[i] = 0;
    if (tid < 2) { xw[tid * 129] = 0; xwI[tid * 129] = 0; }

    const float* xr = x + (size_t)b * SEQL;
    const int* pr = perms + (size_t)b * SEQL;

    // pack direct bits via ballot
#pragma unroll
    for (int it = 0; it < 8; ++it) {
        const int i = it * 512 + tid;
        const unsigned long long m = __ballot(xr[i] > 0.5f);
        if (lane == 0) {
            const int w = 1 + ((it * 512 + (tid & ~63)) >> 5);
            xw[w] = (uint)m;
            xw[w + 1] = (uint)(m >> 32);
        }
    }
    __syncthreads();

    // gather interleaved bits via ballot
#pragma unroll
    for (int it = 0; it < 8; ++it) {
        const int i = it * 512 + tid;
        const int p = pr[i];
        const unsigned long long m = __ballot(((xw[1 + (p >> 5)] >> (p & 31)) & 1u) != 0u);
        if (lane == 0) {
            const int w = 1 + ((it * 512 + (tid & ~63)) >> 5);
            xwI[w] = (uint)m;
            xwI[w + 1] = (uint)(m >> 32);
        }
    }
    __syncthreads();

    // 8 consecutive positions per thread: codes + LDS hist
    const int t0 = tid * 8;
    const int w = (t0 + 30) >> 5;
    const int sh0 = (t0 + 30) & 31;
    const unsigned long long Wd = (unsigned long long)xw[w] | ((unsigned long long)xw[w + 1] << 32);
    const unsigned long long Wi = (unsigned long long)xwI[w] | ((unsigned long long)xwI[w + 1] << 32);
    int c[8];
#pragma unroll
    for (int r = 0; r < 8; ++r) {
        const int t = t0 + r;
        const int type = pat_type(t);
        const int qd = type * 32 + (int)((Wd >> (sh0 + r)) & 31ull);
        const int qp = type * 32 + (int)((Wi >> (sh0 + r)) & 31ull);
        atomicAdd(&h[qd], 1u);
        atomicAdd(&h[NPAT + qp], 1u);
        c[r] = qd | (qp << 8);
    }
    uint4 cv;
    cv.x = (uint)(c[0] | (c[1] << 16));
    cv.y = (uint)(c[2] | (c[3] << 16));
    cv.z = (uint)(c[4] | (c[5] << 16));
    cv.w = (uint)(c[6] | (c[7] << 16));
    *(uint4*)(codes + (size_t)b * SEQL + t0) = cv;
    __syncthreads();

    if (tid < 2 * NPAT) part[tid * 256 + b] = h[tid];
}

// ---------------- k_etab2: reduce partials + wave-parallel e-table -------------
// 120 blocks: j = blk/40, waves handle pattern (blk%40)*4 + wave.
__global__ __launch_bounds__(256) void k_etab2(PtrPack pk,
                                               const uint* __restrict__ part,
                                               float* __restrict__ e_tab,
                                               uint* __restrict__ hr) {
    const int tid = threadIdx.x;
    const int j = blockIdx.x / 40;
    const int qbase = (blockIdx.x % 40) * 4;
    const int wv = tid >> 6, lane = tid & 63;
    const float* Wc = pk.p[6 * j + 0];
    const float* bc = pk.p[6 * j + 1];
    const float* g  = pk.p[6 * j + 2];
    const float* be = pk.p[6 * j + 3];
    const float* Wf = pk.p[6 * j + 4];
    const float  bf = pk.p[6 * j + 5][0];
    const int binBase = (j == 2) ? NPAT : 0;

    __shared__ float sn[NPAT];
    __shared__ float m6part[21][8];
    __shared__ float sM6[21];
    __shared__ float sa[5][DIMC];
    __shared__ float sb[DIMC];
    __shared__ float swf[DIMC];

    // reduce this stream's 160 bins from 256 per-block partials
    for (int p = 0; p < 40; ++p) {
        const int bl = p * 4 + wv;
        const uint4 v = *(const uint4*)&part[(size_t)(binBase + bl) * 256 + lane * 4];
        uint s = v.x + v.y + v.z + v.w;
#pragma unroll
        for (int off = 32; off; off >>= 1) s += __shfl_xor(s, off);
        if (lane == 0) {
            sn[bl] = (float)s;
            hr[binBase + bl] = s;   // duplicate same-value writes across blocks: benign
        }
    }
    __syncthreads();

    // M6 partials: 21 entries x 8 bin-chunks
    if (tid < 168) {
        const int e = tid >> 3, prt = tid & 7;
        int k = 0, rem = e;
        while (rem > 5 - k) { rem -= 6 - k; ++k; }
        const int l = k + rem;
        float S = 0.0f;
        for (int q = prt * 20; q < prt * 20 + 20; ++q)
            S += sn[q] * tap6(q, k) * tap6(q, l);
        m6part[e][prt] = S;
    }
    __syncthreads();
    if (tid < 21) {
        float S = 0.0f;
#pragma unroll
        for (int p = 0; p < 8; ++p) S += m6part[tid][p];
        sM6[tid] = S;
    }
    __syncthreads();

    // per-channel BN coefficients (exact stats via quadratic form)
    {
        const int cch = tid;
        float w6[6];
#pragma unroll
        for (int k = 0; k < 5; ++k) w6[k] = Wc[k * DIMC + cch];
        w6[5] = bc[cch];
        double Ey = 0.0, Ey2 = 0.0;
        int e = 0;
        for (int k = 0; k < 6; ++k) {
            Ey += (double)w6[k] * (double)sM6[tri_idx(k, 5)];
            for (int l = k; l < 6; ++l, ++e) {
                const double p = (double)w6[k] * (double)w6[l] * (double)sM6[e];
                Ey2 += (l == k) ? p : 2.0 * p;
            }
        }
        const double mean = Ey / (double)CNT;
        const double var = Ey2 / (double)CNT - mean * mean;
        const float scale = g[cch] * rsqrtf((float)var + EPS);
#pragma unroll
        for (int k = 0; k < 5; ++k) sa[k][cch] = scale * w6[k];
        sb[cch] = scale * (w6[5] - (float)mean) + be[cch];
        swf[cch] = Wf[cch];
    }
    __syncthreads();

    // one wave per pattern
    const int q = qbase + wv;
    float tk[5];
#pragma unroll
    for (int k = 0; k < 5; ++k) tk[k] = tap6(q, k);
    float acc = 0.0f;
#pragma unroll
    for (int i = 0; i < 4; ++i) {
        const int cch = lane + 64 * i;
        float bn = sb[cch];
#pragma unroll
        for (int k = 0; k < 5; ++k) bn += tk[k] * sa[k][cch];
        acc += fast_elu(bn) * swf[cch];
    }
#pragma unroll
    for (int off = 32; off; off >>= 1) acc += __shfl_xor(acc, off);
    if (lane == 0) e_tab[j * NPAT + q] = acc + bf;
}

// ---------------- k_outtab2: middle+output units -> final output table ---------
__global__ __launch_bounds__(1024) void k_outtab2(const uint* __restrict__ hr,
                                                  const float* __restrict__ e_tab,
                                                  const float* __restrict__ Wm,
                                                  const float* __restrict__ gm,
                                                  const float* __restrict__ bem,
                                                  const float* __restrict__ Wo,
                                                  const float* __restrict__ bo,
                                                  const float* __restrict__ go,
                                                  const float* __restrict__ beo,
                                                  float* __restrict__ out_tab) {
    const int tid = threadIdx.x;
    const int lane = tid & 63, wv = tid >> 6;  // 16 waves

    __shared__ float se[3 * NPAT];
    __shared__ float snn[3 * NPAT];
    __shared__ float sA[DIMC], sB[DIMC], sWo0[DIMC], sWo1[DIMC];
    __shared__ float spre0[3 * NPAT], spre1[3 * NPAT];
    __shared__ double wpart[16][4];
    __shared__ double dstat[6];

    if (tid < 3 * NPAT) {
        se[tid] = e_tab[tid];
        snn[tid] = (float)hr[(tid >= 2 * NPAT) ? (tid - NPAT) : (tid % NPAT)];
    }
    __syncthreads();

    // yt mean/var
    {
        double d1 = 0.0, d2 = 0.0;
        if (tid < 3 * NPAT) {
            const double n = (double)snn[tid], e = (double)se[tid];
            d1 = n * e; d2 = n * e * e;
        }
#pragma unroll
        for (int off = 32; off; off >>= 1) {
            d1 += __shfl_xor(d1, off);
            d2 += __shfl_xor(d2, off);
        }
        if (lane == 0) { wpart[wv][0] = d1; wpart[wv][1] = d2; }
        __syncthreads();
        if (wv == 0) {
            double a = (lane < 16) ? wpart[lane][0] : 0.0;
            double bq = (lane < 16) ? wpart[lane][1] : 0.0;
#pragma unroll
            for (int off = 8; off; off >>= 1) {
                a += __shfl_xor(a, off);
                bq += __shfl_xor(bq, off);
            }
            if (lane == 0) { dstat[0] = a; dstat[1] = bq; }
        }
        __syncthreads();
    }
    const double mean_yt = dstat[0] / (3.0 * (double)CNT);
    const double var_yt  = dstat[1] / (3.0 * (double)CNT) - mean_yt * mean_yt;

    if (tid < DIMC) {
        const float wm = Wm[tid];
        sA[tid] = gm[tid] * wm * rsqrtf(wm * wm * (float)var_yt + EPS);
        sB[tid] = bem[tid];
        sWo0[tid] = Wo[tid * 2 + 0];
        sWo1[tid] = Wo[tid * 2 + 1];
    }
    __syncthreads();

    const float bo0 = bo[0], bo1 = bo[1];
    for (int idx = wv; idx < 3 * NPAT; idx += 16) {
        const float du = se[idx] - (float)mean_yt;
        float a0 = 0.0f, a1 = 0.0f;
#pragma unroll
        for (int i = 0; i < 4; ++i) {
            const int cch = lane + 64 * i;
            const float mo = fast_elu(sA[cch] * du + sB[cch]);
            a0 += mo * sWo0[cch];
            a1 += mo * sWo1[cch];
        }
#pragma unroll
        for (int off = 32; off; off >>= 1) {
            a0 += __shfl_xor(a0, off);
            a1 += __shfl_xor(a1, off);
        }
        if (lane == 0) { spre0[idx] = a0 + bo0; spre1[idx] = a1 + bo1; }
    }
    __syncthreads();

    {
        double v[4] = {0.0, 0.0, 0.0, 0.0};
        if (tid < 3 * NPAT) {
            const double n = (double)snn[tid];
            const double p0 = (double)spre0[tid], p1 = (double)spre1[tid];
            v[0] = n * p0; v[1] = n * p0 * p0; v[2] = n * p1; v[3] = n * p1 * p1;
        }
#pragma unroll
        for (int off = 32; off; off >>= 1)
#pragma unroll
            for (int s = 0; s < 4; ++s) v[s] += __shfl_xor(v[s], off);
        if (lane == 0)
#pragma unroll
            for (int s = 0; s < 4; ++s) wpart[wv][s] = v[s];
        __syncthreads();
        if (wv == 0) {
            double a[4];
#pragma unroll
            for (int s = 0; s < 4; ++s) a[s] = (lane < 16) ? wpart[lane][s] : 0.0;
#pragma unroll
            for (int off = 8; off; off >>= 1)
#pragma unroll
                for (int s = 0; s < 4; ++s) a[s] += __shfl_xor(a[s], off);
            if (lane == 0)
#pragma unroll
                for (int s = 0; s < 4; ++s) dstat[2 + s] = a[s];
        }
        __syncthreads();
    }

    if (tid < 3 * NPAT) {
        const double m0 = dstat[2] / (3.0 * (double)CNT);
        const double v0 = dstat[3] / (3.0 * (double)CNT) - m0 * m0;
        const double m1 = dstat[4] / (3.0 * (double)CNT);
        const double v1 = dstat[5] / (3.0 * (double)CNT) - m1 * m1;
        const float sc0 = go[0] * rsqrtf((float)v0 + EPS);
        const float sc1 = go[1] * rsqrtf((float)v1 + EPS);
        out_tab[tid * 2 + 0] = sc0 * (spre0[tid] - (float)m0) + beo[0];
        out_tab[tid * 2 + 1] = sc1 * (spre1[tid] - (float)m1) + beo[1];
    }
}

// ---------------- k_write2: streaming table write from codes -------------------
// 1024 blocks x 256 threads, 4 consecutive positions per thread.
__global__ __launch_bounds__(256) void k_write2(const ushort_t* __restrict__ codes,
                                                const float* __restrict__ out_tab,
                                                float* __restrict__ out) {
    __shared__ float2 tb[3 * NPAT];
    const int tid = threadIdx.x;
    for (int i = tid; i < 3 * NPAT; i += 256) tb[i] = ((const float2*)out_tab)[i];
    __syncthreads();
    const size_t gidx = (size_t)blockIdx.x * 256 + tid;
    const ushort4 cv = ((const ushort4*)codes)[gidx];
    const int cc[4] = {cv.x, cv.y, cv.z, cv.w};
    union { float f[24]; float4 v[6]; } u;
#pragma unroll
    for (int r = 0; r < 4; ++r) {
        const int qd = cc[r] & 0xff, qp = cc[r] >> 8;
        const float2 v0 = tb[qd], v1 = tb[NPAT + qd], v2 = tb[2 * NPAT + qp];
        u.f[r * 6 + 0] = v0.x; u.f[r * 6 + 1] = v0.y;
        u.f[r * 6 + 2] = v1.x; u.f[r * 6 + 3] = v1.y;
        u.f[r * 6 + 4] = v2.x; u.f[r * 6 + 5] = v2.y;
    }
    float4* o = (float4*)(out + gidx * 24);
#pragma unroll
    for (int r = 0; r < 6; ++r) o[r] = u.v[r];
}

// =============================================================================
// PATH B (fallback, proven round-2 pipeline) — used only if ws_size is small
// =============================================================================
__global__ __launch_bounds__(256) void k_hist(const float* __restrict__ x,
                                              const int* __restrict__ perms,
                                              unsigned int* __restrict__ hist) {
    __shared__ unsigned char xb[SEQL];
    __shared__ unsigned char xbI[SEQL];
    __shared__ unsigned int h[2 * NPAT];
    const int b = blockIdx.x, tid = threadIdx.x;
    for (int i = tid; i < 2 * NPAT; i += 256) h[i] = 0;
    const float* xr = x + (size_t)b * SEQL;
    const int* pr = perms + (size_t)b * SEQL;
    for (int i = tid; i < SEQL; i += 256) xb[i] = xr[i] > 0.5f ? 1 : 0;
    __syncthreads();
    for (int i = tid; i < SEQL; i += 256) xbI[i] = xb[pr[i]];
    __syncthreads();
    for (int t = tid; t < SEQL; t += 256) {
        atomicAdd(&h[pat_q(xb, t)], 1u);
        atomicAdd(&h[NPAT + pat_q(xbI, t)], 1u);
    }
    __syncthreads();
    for (int i = tid; i < 2 * NPAT; i += 256)
        if (h[i]) atomicAdd(&hist[i], h[i]);
}

__global__ __launch_bounds__(256) void k_write(const float* __restrict__ x,
                                               const int* __restrict__ perms,
                                               const float* __restrict__ out_tab,
                                               float* __restrict__ out) {
    __shared__ unsigned char xb[SEQL];
    __shared__ unsigned char xbI[SEQL];
    __shared__ float tb[3 * NPAT * 2];
    const int b = blockIdx.x, tid = threadIdx.x;
    for (int i = tid; i < 3 * NPAT * 2; i += 256) tb[i] = out_tab[i];
    const float* xr = x + (size_t)b * SEQL;
    const int* pr = perms + (size_t)b * SEQL;
    for (int i = tid; i < SEQL; i += 256) xb[i] = xr[i] > 0.5f ? 1 : 0;
    __syncthreads();
    for (int i = tid; i < SEQL; i += 256) xbI[i] = xb[pr[i]];
    __syncthreads();
    float* ob = out + (size_t)b * (3 * SEQL * 2);
    for (int t = tid; t < SEQL; t += 256) {
        const int qd = pat_q(xb, t);
        const int qp = pat_q(xbI, t);
        const float2 v0 = *(const float2*)&tb[(0 * NPAT + qd) * 2];
        const float2 v1 = *(const float2*)&tb[(1 * NPAT + qd) * 2];
        const float2 v2 = *(const float2*)&tb[(2 * NPAT + qp) * 2];
        float2* o = (float2*)(ob + (size_t)t * 6);
        o[0] = v0; o[1] = v1; o[2] = v2;
    }
}

// legacy etab/outtab operating on a directly-accumulated global hist
__global__ __launch_bounds__(256) void k_etab_legacy(PtrPack pk,
                                                     const unsigned int* __restrict__ hist,
                                                     float* __restrict__ e_tab,
                                                     uint* __restrict__ hr) {
    // copy hist to hr once (blocks 0 and 80), then same pipeline via sn
    const int tid = threadIdx.x;
    const int j = blockIdx.x / 40;
    const int qbase = (blockIdx.x % 40) * 4;
    const int wv = tid >> 6, lane = tid & 63;
    const float* Wc = pk.p[6 * j + 0];
    const float* bc = pk.p[6 * j + 1];
    const float* g  = pk.p[6 * j + 2];
    const float* be = pk.p[6 * j + 3];
    const float* Wf = pk.p[6 * j + 4];
    const float  bf = pk.p[6 * j + 5][0];
    const unsigned int* hj = hist + (j == 2 ? NPAT : 0);

    __shared__ float sn[NPAT];
    __shared__ float m6part[21][8];
    __shared__ float sM6[21];
    __shared__ float sa[5][DIMC];
    __shared__ float sb[DIMC];
    __shared__ float swf[DIMC];

    if (tid < NPAT) {
        const uint n = hj[tid];
        sn[tid] = (float)n;
        hr[(j == 2 ? NPAT : 0) + tid] = n;
    }
    __syncthreads();

    if (tid < 168) {
        const int e = tid >> 3, prt = tid & 7;
        int k = 0, rem = e;
        while (rem > 5 - k) { rem -= 6 - k; ++k; }
        const int l = k + rem;
        float S = 0.0f;
        for (int q = prt * 20; q < prt * 20 + 20; ++q)
            S += sn[q] * tap6(q, k) * tap6(q, l);
        m6part[e][prt] = S;
    }
    __syncthreads();
    if (tid < 21) {
        float S = 0.0f;
#pragma unroll
        for (int p = 0; p < 8; ++p) S += m6part[tid][p];
        sM6[tid] = S;
    }
    __syncthreads();

    {
        const int cch = tid;
        float w6[6];
#pragma unroll
        for (int k = 0; k < 5; ++k) w6[k] = Wc[k * DIMC + cch];
        w6[5] = bc[cch];
        double Ey = 0.0, Ey2 = 0.0;
        int e = 0;
        for (int k = 0; k < 6; ++k) {
            Ey += (double)w6[k] * (double)sM6[tri_idx(k, 5)];
            for (int l = k; l < 6; ++l, ++e) {
                const double p = (double)w6[k] * (double)w6[l] * (double)sM6[e];
                Ey2 += (l == k) ? p : 2.0 * p;
            }
        }
        const double mean = Ey / (double)CNT;
        const double var = Ey2 / (double)CNT - mean * mean;
        const float scale = g[cch] * rsqrtf((float)var + EPS);
#pragma unroll
        for (int k = 0; k < 5; ++k) sa[k][cch] = scale * w6[k];
        sb[cch] = scale * (w6[5] - (float)mean) + be[cch];
        swf[cch] = Wf[cch];
    }
    __syncthreads();

    const int q = qbase + wv;
    float tk[5];
#pragma unroll
    for (int k = 0; k < 5; ++k) tk[k] = tap6(q, k);
    float acc = 0.0f;
#pragma unroll
    for (int i = 0; i < 4; ++i) {
        const int cch = lane + 64 * i;
        float bn = sb[cch];
#pragma unroll
        for (int k = 0; k < 5; ++k) bn += tk[k] * sa[k][cch];
        acc += fast_elu(bn) * swf[cch];
    }
#pragma unroll
    for (int off = 32; off; off >>= 1) acc += __shfl_xor(acc, off);
    if (lane == 0) e_tab[j * NPAT + q] = acc + bf;
}

// =============================================================================
extern "C" void kernel_launch(void* const* d_in, const int* in_sizes, int n_in,
                              void* d_out, int out_size, void* d_ws, size_t ws_size,
                              hipStream_t stream) {
    (void)in_sizes; (void)n_in; (void)out_size;
    const float* x = (const float*)d_in[0];
    const int* perms = (const int*)d_in[1];

    PtrPack pk;
    for (int j = 0; j < 3; ++j)
        for (int s = 0; s < 6; ++s)
            pk.p[6 * j + s] = (const float*)d_in[2 + 6 * j + s];

    const float* Wm  = (const float*)d_in[20];
    const float* gm  = (const float*)d_in[22];
    const float* bem = (const float*)d_in[23];
    const float* Wo  = (const float*)d_in[24];
    const float* bo  = (const float*)d_in[25];
    const float* go  = (const float*)d_in[26];
    const float* beo = (const float*)d_in[27];

    // path A ws layout
    const size_t OFF_PART  = 0;                       // 320*256 u32 = 327680
    const size_t OFF_ETAB  = 327680;                  // 480 f32
    const size_t OFF_OUTT  = 329600;                  // 960 f32
    const size_t OFF_HR    = 333440;                  // 320 u32
    const size_t OFF_CODES = 334720;                  // 1M u16 = 2 MB
    const size_t NEED_A    = OFF_CODES + (size_t)BATCH * SEQL * 2;

    if (ws_size >= NEED_A) {
        uint*     part    = (uint*)d_ws;
        float*    e_tab   = (float*)((char*)d_ws + OFF_ETAB);
        float*    out_tab = (float*)((char*)d_ws + OFF_OUTT);
        uint*     hr      = (uint*)((char*)d_ws + OFF_HR);
        ushort_t* codes   = (ushort_t*)((char*)d_ws + OFF_CODES);

        k_prep<<<BATCH, 512, 0, stream>>>(x, perms, part, codes);
        k_etab2<<<120, 256, 0, stream>>>(pk, part, e_tab, hr);
        k_outtab2<<<1, 1024, 0, stream>>>(hr, e_tab, Wm, gm, bem, Wo, bo, go, beo, out_tab);
        k_write2<<<1024, 256, 0, stream>>>(codes, out_tab, (float*)d_out);
    } else {
        // fallback: ws layout [0,1280) hist; [1280,3200) e_tab; [3200,7040) out_tab; [7040,8320) hr
        unsigned int* hist   = (unsigned int*)d_ws;
        float* e_tab  = (float*)((char*)d_ws + 1280);
        float* out_tab = (float*)((char*)d_ws + 3200);
        uint* hr = (uint*)((char*)d_ws + 7040);

        hipMemsetAsync(d_ws, 0, 1280, stream);
        k_hist<<<BATCH, 256, 0, stream>>>(x, perms, hist);
        k_etab_legacy<<<120, 256, 0, stream>>>(pk, hist, e_tab, hr);
        k_outtab2<<<1, 1024, 0, stream>>>(hr, e_tab, Wm, gm, bem, Wo, bo, go, beo, out_tab);
        k_write<<<BATCH, 256, 0, stream>>>(x, perms, out_tab, (float*)d_out);
    }
}